// Round 5
// baseline (751.127 us; speedup 1.0000x reference)
//
#include <hip/hip_runtime.h>
#include <cstddef>

// ============================================================================
// VLSTM via bf16 MFMA, R9: 4 waves/SIMD via L2-streamed weights + 2-pass gates.
//  - R8 lesson: per-node-step time invariant => stall-bound, not overhead-
//    bound. 2 lockstep waves/SIMD can't hide trans/LDS/MFMA latency.
//  - Weights NOT register-resident: B-frags streamed from global per use.
//    All 512 blocks co-resident read the same 192 KB/step -> XCD-L2 hits
//    (~40 B/cyc/CU, under the ~56 budget). (R3's HBM blowup was 2 skewed
//    rounds; single co-resident round is the L2-friendly case.)
//  - 2-pass gate schedule bounds live regs: pass1 (i,g) -> P = sig(i)*ggL
//    (16 f32); pass2 (f,o) -> final ACT. Pure reassociation: bit-identical.
//  - MT=64, GRID=512, __launch_bounds__(512,4): 2 blocks/CU, 16 waves/CU,
//    independent barriers -> latency hiding across blocks.
//  - Keeps: A dbuf 1 barrier/step, ballot mask, prescaled log2-domain
//    activations, direct OPROJ store, coalesced epilogues.
// ============================================================================

typedef __attribute__((ext_vector_type(8))) short  s16x8;   // 8 x bf16
typedef __attribute__((ext_vector_type(4))) float  f32x4;

namespace {
constexpr int T_STEPS = 20;
constexpr int NN      = 32768;
constexpr int D_EMB   = 64;
constexpr int D_H     = 128;
constexpr int D_OUT   = 5;
constexpr int G4      = 512;
constexpr int MT      = 64;                   // nodes per block
constexpr int BLOCK   = 512;
constexpr int GRID    = NN / MT;              // 512 blocks = 2/CU co-resident
constexpr int RT_N    = MT / 16;              // 4 row-tiles
constexpr int WP_ELEMS   = 8 * 4 * 6 * 64 * 8;
constexpr int WOUT_ELEMS = 4 * 64 * 8;
constexpr int A_ELEMS    = RT_N * 6 * 64 * 8;   // 12288 shorts = 24 KB / buf
constexpr float LOG2E = 1.4426950408889634f;
constexpr float AM4   = -4.0f * LOG2E;
constexpr float AP2   =  2.0f * LOG2E;
constexpr float CINV  = 0.34657359027997264f;   // 1/(2*log2e)
constexpr size_t OFF_H = (size_t)T_STEPS * NN * D_OUT;
constexpr size_t OFF_C = OFF_H + (size_t)NN * D_H;
}

__device__ __forceinline__ unsigned short f2bf(float x) {
    unsigned u = __float_as_uint(x);
    u = (u + 0x7FFFu + ((u >> 16) & 1u)) >> 16;     // RNE
    return (unsigned short)u;
}
__device__ __forceinline__ unsigned short f2bf_hw(float x) {
    __bf16 b = (__bf16)x;
    union { __bf16 b; unsigned short u; } cv;
    cv.b = b;
    return cv.u;
}
__device__ __forceinline__ float bf2f(unsigned short h) {
    return __uint_as_float(((unsigned)h) << 16);
}
__device__ __forceinline__ float exp2f_fast(float x) {
#if __has_builtin(__builtin_amdgcn_exp2f)
    return __builtin_amdgcn_exp2f(x);
#else
    return __expf(x * 0.6931471805599453f);
#endif
}
__device__ __forceinline__ float sig_pre(float a) {   // sigmoid, a = -x*log2e
    return __builtin_amdgcn_rcpf(1.0f + exp2f_fast(a));
}

// ----------------------------------------------------------------------------
__global__ void prepack_kernel(const float* __restrict__ W_ih,
                               const float* __restrict__ b_ih,
                               const float* __restrict__ W_hh,
                               const float* __restrict__ b_hh,
                               const float* __restrict__ W_out,
                               unsigned short* __restrict__ Wp,
                               unsigned short* __restrict__ WoutF,
                               float* __restrict__ b_sum) {
    int idx = blockIdx.x * blockDim.x + threadIdx.x;
    if (idx < WP_ELEMS) {
        int j    = idx & 7;
        int L    = (idx >> 3) & 63;
        int rest = idx >> 9;
        int kb   = rest % 6;
        int gw   = rest / 6;
        int g    = gw & 3, w = gw >> 2;
        int k    = kb * 32 + (L >> 4) * 8 + j;
        int col  = g * D_H + w * 16 + (L & 15);
        float v  = (k < D_EMB) ? W_ih[k * G4 + col] : W_hh[(k - D_EMB) * G4 + col];
        float s  = (g == 2) ? (2.0f * LOG2E) : (-LOG2E);
        Wp[idx] = f2bf(v * s);
    } else if (idx < WP_ELEMS + WOUT_ELEMS) {
        int i2 = idx - WP_ELEMS;
        int j = i2 & 7, L = (i2 >> 3) & 63, kb2 = i2 >> 9;
        int k = kb2 * 32 + (L >> 4) * 8 + j;
        int n = L & 15;
        WoutF[i2] = (n < D_OUT) ? f2bf(W_out[k * D_OUT + n]) : (unsigned short)0;
    }
    if (idx < G4) {
        int g = idx / D_H;
        float s = (g == 2) ? (2.0f * LOG2E) : (-LOG2E);
        b_sum[idx] = (b_ih[idx] + b_hh[idx]) * s;
    }
}

// ----------------------------------------------------------------------------
__global__ __launch_bounds__(BLOCK, 4) void vlstm_kernel(
    const float* __restrict__ nodes,   // [T][N][2]
    const int*   __restrict__ mask,    // [T][N]
    const float* __restrict__ h0,      // [N][128]
    const float* __restrict__ c0,      // [N][128]
    const float* __restrict__ W_embed, // [2][64]
    const float* __restrict__ b_embed, // [64]
    const float* __restrict__ b_out,   // [5]
    const unsigned short* __restrict__ Wp,
    const unsigned short* __restrict__ WoutF,
    const float* __restrict__ b_sum,
    float* __restrict__ out)
{
    __shared__ __align__(16) unsigned short A[2][A_ELEMS];   // 48 KB dbuf
    __shared__ __align__(16) unsigned short WoS[WOUT_ELEMS]; // 4 KB
    __shared__ float We_s[2 * D_EMB];
    __shared__ float be_s[D_EMB];
    __shared__ unsigned long long msk64[2];

    const int tid  = threadIdx.x;
    const int wave = tid >> 6;
    const int L    = tid & 63;
    const int quad = L >> 4;
    const int l15  = L & 15;
    const int n_base = blockIdx.x * MT;

    // per-wave weight base (frags streamed from L2 each use, NOT reg-resident)
    const unsigned short* __restrict__ wbase = Wp + (size_t)wave * (4 * 6 * 64 * 8);

    const int u_lane = wave * 16 + l15;
    float bias[4];
    #pragma unroll
    for (int g = 0; g < 4; g++) bias[g] = b_sum[g * D_H + u_lane];
    const float bo = (l15 < D_OUT) ? b_out[l15] : 0.0f;

    // per-thread A h-row write geometry
    const int kb_u = 2 + (u_lane >> 5);
    const int fl   = ((u_lane >> 3) & 3) * 16 + quad * 4;
    const int j_u  = u_lane & 7;

    // ---- one-time LDS staging ----
    for (int i = tid; i < 3 * D_EMB; i += BLOCK) {
        if (i < 2 * D_EMB) We_s[i] = W_embed[i];
        else               be_s[i - 2 * D_EMB] = b_embed[i - 2 * D_EMB];
    }
    for (int i = tid; i < WOUT_ELEMS; i += BLOCK) WoS[i] = WoutF[i];

    // ---- h, c -> registers (c as cL = 2c*log2e); h -> A[0] h-rows ----
    float          cL[RT_N][4];
    unsigned short hr[RT_N][4];
    #pragma unroll
    for (int rt = 0; rt < RT_N; rt++)
        #pragma unroll
        for (int r = 0; r < 4; r++) {
            int m = rt * 16 + quad * 4 + r;
            cL[rt][r] = AP2 * c0[(size_t)(n_base + m) * D_H + u_lane];
            hr[rt][r] = f2bf_hw(h0[(size_t)(n_base + m) * D_H + u_lane]);
            A[0][((rt * 6 + kb_u) * 64 + fl + r) * 8 + j_u] = hr[rt][r];
        }

    // ---- emb mapping: 8 threads/node, 8 emb dims each ----
    const int node_e = tid >> 3;
    const int eb     = tid & 7;
    const int idx_e  = (((node_e >> 4) * 6 + (eb >> 2)) * 64 + (eb & 3) * 16 + (node_e & 15)) * 8;

#define EMB_WRITE(AW, XV) do {                                                 \
    s16x8 ev;                                                                  \
    _Pragma("unroll")                                                          \
    for (int j = 0; j < 8; j++) {                                              \
        int e = eb * 8 + j;                                                    \
        float v = fmaf((XV).x, We_s[e], fmaf((XV).y, We_s[D_EMB + e], be_s[e])); \
        ev[j] = (short)f2bf_hw(fmaxf(v, 0.0f));                                \
    }                                                                          \
    *(s16x8*)((AW) + idx_e) = ev;                                              \
} while (0)

    // ---- emb(0) + mask(0) -> A[0] ----
    {
        float2 x0 = *(const float2*)(nodes + (size_t)(n_base + node_e) * 2);
        EMB_WRITE(A[0], x0);
        if (wave == 0) {
            int lm0 = mask[n_base + L];
            unsigned long long bm0 = __ballot(lm0 != 0);
            if (L == 0) msk64[0] = bm0;
        }
    }
    __syncthreads();   // prologue barrier

// One gate-pair GEMM pass: gates GA,GB streamed from L2, acc[rt][0/1].
#define PASS(GA, GB) do {                                                      \
    _Pragma("unroll")                                                          \
    for (int kb = 0; kb < 6; kb++) {                                           \
        s16x8 ba = *(const s16x8*)(wbase + (((GA) * 6 + kb) * 64 + L) * 8);    \
        s16x8 bb = *(const s16x8*)(wbase + (((GB) * 6 + kb) * 64 + L) * 8);    \
        _Pragma("unroll")                                                      \
        for (int rt = 0; rt < RT_N; rt++) {                                    \
            s16x8 af = *(const s16x8*)(Ar + ((rt * 6 + kb) * 64 + L) * 8);     \
            if (kb == 0) {                                                     \
                acc[rt][0] = __builtin_amdgcn_mfma_f32_16x16x32_bf16(          \
                    af, ba, (f32x4){0.f, 0.f, 0.f, 0.f}, 0, 0, 0);             \
                acc[rt][1] = __builtin_amdgcn_mfma_f32_16x16x32_bf16(          \
                    af, bb, (f32x4){0.f, 0.f, 0.f, 0.f}, 0, 0, 0);             \
            } else {                                                           \
                acc[rt][0] = __builtin_amdgcn_mfma_f32_16x16x32_bf16(          \
                    af, ba, acc[rt][0], 0, 0, 0);                              \
                acc[rt][1] = __builtin_amdgcn_mfma_f32_16x16x32_bf16(          \
                    af, bb, acc[rt][1], 0, 0, 0);                              \
            }                                                                  \
        }                                                                      \
    }                                                                          \
} while (0)

// out-proj for time TIDX from buffer ARP (h rows), mask word MP (regs),
// waves 0..3 (rt = wave), direct masked global store (contiguous 320B/wave).
#define OPROJ(ARP, TIDX, MP) do {                                              \
    f32x4 ao = (f32x4){0.f, 0.f, 0.f, 0.f};                                    \
    _Pragma("unroll")                                                          \
    for (int kb2 = 0; kb2 < 4; kb2++) {                                        \
        s16x8 af = *(const s16x8*)((ARP) + ((wave * 6 + 2 + kb2) * 64 + L) * 8); \
        s16x8 wf = *(const s16x8*)(WoS + (kb2 * 64 + L) * 8);                  \
        ao = __builtin_amdgcn_mfma_f32_16x16x32_bf16(af, wf, ao, 0, 0, 0);     \
    }                                                                          \
    if (l15 < D_OUT) {                                                         \
        unsigned nib = (unsigned)((MP) >> (wave * 16 + quad * 4)) & 0xFu;      \
        float* ob = out + ((size_t)(TIDX) * NN + n_base) * D_OUT + l15;        \
        _Pragma("unroll")                                                      \
        for (int r = 0; r < 4; r++) {                                          \
            int node = wave * 16 + quad * 4 + r;                               \
            ob[node * D_OUT] = ((nib >> r) & 1u) ? (ao[r] + bo) : 0.0f;        \
        }                                                                      \
    } } while (0)

    unsigned long long Mp = 0;

    for (int t = 0; t < T_STEPS; t++) {
        unsigned short* __restrict__ Ar = A[t & 1];
        unsigned short* __restrict__ Aw = A[(t + 1) & 1];
        const unsigned long long M = msk64[t & 1];

        // prefetch x(t+1)/mask(t+1)
        float2 xv = make_float2(0.0f, 0.0f);
        int    lm = 0;
        if (t + 1 < T_STEPS) {
            xv = *(const float2*)(nodes + ((size_t)(t + 1) * NN + n_base + node_e) * 2);
            if (wave == 0) lm = mask[(size_t)(t + 1) * NN + n_base + L];
        }

        f32x4 acc[RT_N][2];

        // ---- PASS 1: gates i (g=0), g (g=2) ----
        PASS(0, 2);

        // collapse to P = sig(i) * ggL  (16 f32; frees acc for pass 2)
        float P[RT_N][4];
        #pragma unroll
        for (int rt = 0; rt < RT_N; rt++)
            #pragma unroll
            for (int r = 0; r < 4; r++) {
                float gi = sig_pre(acc[rt][0][r] + bias[0]);
                float rg = sig_pre(acc[rt][1][r] + bias[2]);
                P[rt][r] = gi * fmaf(AM4, rg, AP2);
            }

        // ---- out-proj(t-1): reads Ar h-rows (stable this step) ----
        if (t > 0 && wave < 4) OPROJ(Ar, t - 1, Mp);

        // ---- PASS 2: gates f (g=1), o (g=3) ----
        PASS(1, 3);

        // ---- final ACT + state update + unconditional h-write to Aw ----
        #pragma unroll
        for (int rt = 0; rt < RT_N; rt++) {
            unsigned nib = (unsigned)(M >> (rt * 16 + quad * 4)) & 0xFu;
            #pragma unroll
            for (int r = 0; r < 4; r++) {
                float gf = sig_pre(acc[rt][0][r] + bias[1]);
                float go = sig_pre(acc[rt][1][r] + bias[3]);
                float cnL = fmaf(gf, cL[rt][r], P[rt][r]);   // 2*log2e*c_new
                float rr  = __builtin_amdgcn_rcpf(1.0f + exp2f_fast(cnL));
                float hv  = go * fmaf(-2.0f, rr, 1.0f);      // o*tanh(c_new)
                unsigned short hb = f2bf_hw(hv);
                if ((nib >> r) & 1u) { cL[rt][r] = cnL; hr[rt][r] = hb; }
                Aw[((rt * 6 + kb_u) * 64 + fl + r) * 8 + j_u] = hr[rt][r];
            }
        }

        // ---- emb(t+1) + mask(t+1) -> Aw ----
        if (t + 1 < T_STEPS) {
            EMB_WRITE(Aw, xv);
            if (wave == 0) {
                unsigned long long bm = __ballot(lm != 0);
                if (L == 0) msk64[(t + 1) & 1] = bm;
            }
        }

        Mp = M;
        __syncthreads();   // THE barrier: nothing runs after it this step
    }

    // ---- epilogue: A[0] holds h(19); Mp = M(19) ----
    if (wave < 4) OPROJ(A[0], T_STEPS - 1, Mp);

    // h_fin: coalesced from A[0]
    for (int i = tid; i < MT * D_H; i += BLOCK) {
        int node = i >> 7, u = i & 127;
        int idx = (((node >> 4) * 6 + 2 + (u >> 5)) * 64 +
                   ((u >> 3) & 3) * 16 + (node & 15)) * 8 + (u & 7);
        out[OFF_H + (size_t)(n_base + node) * D_H + u] = bf2f(A[0][idx]);
    }

    // c_fin: LDS staging (stride 129, conflict-free), coalesced copy
    __syncthreads();                    // all A reads done
    float* cs = (float*)A;              // 64*129*4 = 33 KB of the 48 KB
    #pragma unroll
    for (int rt = 0; rt < RT_N; rt++)
        #pragma unroll
        for (int r = 0; r < 4; r++) {
            int m = rt * 16 + quad * 4 + r;
            cs[m * 129 + u_lane] = CINV * cL[rt][r];
        }
    __syncthreads();
    for (int i = tid; i < MT * D_H; i += BLOCK) {
        int node = i >> 7, u = i & 127;
        out[OFF_C + (size_t)(n_base + node) * D_H + u] = cs[node * 129 + u];
    }

#undef EMB_WRITE
#undef PASS
#undef OPROJ
}

extern "C" void kernel_launch(void* const* d_in, const int* in_sizes, int n_in,
                              void* d_out, int out_size, void* d_ws, size_t ws_size,
                              hipStream_t stream) {
    const float* nodes   = (const float*)d_in[0];
    const int*   mask    = (const int*)  d_in[1];
    const float* h0      = (const float*)d_in[2];
    const float* c0      = (const float*)d_in[3];
    const float* W_embed = (const float*)d_in[4];
    const float* b_embed = (const float*)d_in[5];
    const float* W_ih    = (const float*)d_in[6];
    const float* b_ih    = (const float*)d_in[7];
    const float* W_hh    = (const float*)d_in[8];
    const float* b_hh    = (const float*)d_in[9];
    const float* W_out   = (const float*)d_in[10];
    const float* b_out   = (const float*)d_in[11];
    float* out = (float*)d_out;

    unsigned short* Wp    = (unsigned short*)d_ws;
    unsigned short* WoutF = Wp + WP_ELEMS;
    float*          b_sum = (float*)(WoutF + WOUT_ELEMS);

    prepack_kernel<<<(WP_ELEMS + WOUT_ELEMS + 255) / 256, 256, 0, stream>>>(
        W_ih, b_ih, W_hh, b_hh, W_out, Wp, WoutF, b_sum);

    vlstm_kernel<<<GRID, BLOCK, 0, stream>>>(
        nodes, mask, h0, c0, W_embed, b_embed, b_out, Wp, WoutF, b_sum, out);
}

// Round 6
// 323.295 us; speedup vs baseline: 2.3233x; 2.3233x over previous
//
#include <hip/hip_runtime.h>
#include <cstddef>

// ============================================================================
// VLSTM via bf16 MFMA, R10: R8 base + LDS XOR-swizzle + bias-C + trans hygiene.
//  - R9 post-mortem: launch_bounds(512,4) forced full spill (VGPR=64, 1.8 GB
//    scratch traffic). 2 waves/SIMD is structural (weights = 96 VGPR/thread
//    floor). Reverted to R8 (MT=128, GRID=256, 1 round, proven 201 us).
//  - A-buffer XOR swizzle (unit16 ^= (unit16>>3)&7): h-writes were 8-way
//    bank-conflicted (quad/hi groups alias 4 banks); now 2-way (free).
//    Reads keep immediate offsets: XOR folds into per-lane constant bases.
//  - bias as MFMA C-operand on kb=0 (R7-proven): -128 VALU adds/wave/step.
//  - exp2 fallback = exp2f() (native v_exp_f32); hr held in 32-bit regs
//    (no subword pack/unpack on the masked state merge).
// ============================================================================

typedef __attribute__((ext_vector_type(8))) short  s16x8;   // 8 x bf16
typedef __attribute__((ext_vector_type(4))) float  f32x4;

namespace {
constexpr int T_STEPS = 20;
constexpr int NN      = 32768;
constexpr int D_EMB   = 64;
constexpr int D_H     = 128;
constexpr int D_OUT   = 5;
constexpr int G4      = 512;
constexpr int MT      = 128;                  // nodes per block
constexpr int BLOCK   = 512;
constexpr int GRID    = NN / MT;              // 256 blocks = 256 CUs
constexpr int RT_N    = MT / 16;              // 8 row-tiles
constexpr int WP_ELEMS   = 8 * 4 * 6 * 64 * 8;
constexpr int WOUT_ELEMS = 4 * 64 * 8;
constexpr int A_ELEMS    = RT_N * 6 * 64 * 8;   // 24576 shorts = 48 KB / buf
constexpr float LOG2E = 1.4426950408889634f;
constexpr float AM4   = -4.0f * LOG2E;
constexpr float AP2   =  2.0f * LOG2E;
constexpr float CINV  = 0.34657359027997264f;   // 1/(2*log2e)
constexpr size_t OFF_H = (size_t)T_STEPS * NN * D_OUT;
constexpr size_t OFF_C = OFF_H + (size_t)NN * D_H;
}

__device__ __forceinline__ unsigned short f2bf(float x) {
    unsigned u = __float_as_uint(x);
    u = (u + 0x7FFFu + ((u >> 16) & 1u)) >> 16;     // RNE
    return (unsigned short)u;
}
__device__ __forceinline__ unsigned short f2bf_hw(float x) {
    __bf16 b = (__bf16)x;
    union { __bf16 b; unsigned short u; } cv;
    cv.b = b;
    return cv.u;
}
__device__ __forceinline__ float bf2f(unsigned short h) {
    return __uint_as_float(((unsigned)h) << 16);
}
__device__ __forceinline__ float exp2f_fast(float x) {
#if __has_builtin(__builtin_amdgcn_exp2f)
    return __builtin_amdgcn_exp2f(x);
#else
    return exp2f(x);                              // ocml native v_exp_f32
#endif
}
__device__ __forceinline__ float sig_pre(float a) {   // sigmoid, a = -x*log2e
    return __builtin_amdgcn_rcpf(1.0f + exp2f_fast(a));
}

// ----------------------------------------------------------------------------
__global__ void prepack_kernel(const float* __restrict__ W_ih,
                               const float* __restrict__ b_ih,
                               const float* __restrict__ W_hh,
                               const float* __restrict__ b_hh,
                               const float* __restrict__ W_out,
                               unsigned short* __restrict__ Wp,
                               unsigned short* __restrict__ WoutF,
                               float* __restrict__ b_sum) {
    int idx = blockIdx.x * blockDim.x + threadIdx.x;
    if (idx < WP_ELEMS) {
        int j    = idx & 7;
        int L    = (idx >> 3) & 63;
        int rest = idx >> 9;
        int kb   = rest % 6;
        int gw   = rest / 6;
        int g    = gw & 3, w = gw >> 2;
        int k    = kb * 32 + (L >> 4) * 8 + j;
        int col  = g * D_H + w * 16 + (L & 15);
        float v  = (k < D_EMB) ? W_ih[k * G4 + col] : W_hh[(k - D_EMB) * G4 + col];
        float s  = (g == 2) ? (2.0f * LOG2E) : (-LOG2E);
        Wp[idx] = f2bf(v * s);
    } else if (idx < WP_ELEMS + WOUT_ELEMS) {
        int i2 = idx - WP_ELEMS;
        int j = i2 & 7, L = (i2 >> 3) & 63, kb2 = i2 >> 9;
        int k = kb2 * 32 + (L >> 4) * 8 + j;
        int n = L & 15;
        WoutF[i2] = (n < D_OUT) ? f2bf(W_out[k * D_OUT + n]) : (unsigned short)0;
    }
    if (idx < G4) {
        int g = idx / D_H;
        float s = (g == 2) ? (2.0f * LOG2E) : (-LOG2E);
        b_sum[idx] = (b_ih[idx] + b_hh[idx]) * s;
    }
}

// ----------------------------------------------------------------------------
__global__ __launch_bounds__(BLOCK, 2) void vlstm_kernel(
    const float* __restrict__ nodes,   // [T][N][2]
    const int*   __restrict__ mask,    // [T][N]
    const float* __restrict__ h0,      // [N][128]
    const float* __restrict__ c0,      // [N][128]
    const float* __restrict__ W_embed, // [2][64]
    const float* __restrict__ b_embed, // [64]
    const float* __restrict__ b_out,   // [5]
    const unsigned short* __restrict__ Wp,
    const unsigned short* __restrict__ WoutF,
    const float* __restrict__ b_sum,
    float* __restrict__ out)
{
    __shared__ __align__(16) unsigned short A[2][A_ELEMS];   // 96 KB dbuf
    __shared__ __align__(16) unsigned short WoS[WOUT_ELEMS]; // 4 KB
    __shared__ float We_s[2 * D_EMB];
    __shared__ float be_s[D_EMB];
    __shared__ __align__(16) unsigned long long msk64[2][2];

    const int tid  = threadIdx.x;
    const int wave = tid >> 6;
    const int L    = tid & 63;
    const int quad = L >> 4;
    const int l15  = L & 15;
    const int n_base = blockIdx.x * MT;

    // swizzled lane base for all A-frag reads (GEMM + OPROJ), in shorts
    const int Lsw = (L * 8) ^ (((L >> 3) & 7) << 3);

    // ---- gate weights -> registers, once (96 VGPR/wave) ----
    const unsigned short* wbase = Wp + (size_t)wave * (4 * 6 * 64 * 8);
    s16x8 Bf[4][6];
    #pragma unroll
    for (int g = 0; g < 4; g++)
        #pragma unroll
        for (int kb = 0; kb < 6; kb++)
            Bf[g][kb] = *(const s16x8*)(wbase + ((g * 6 + kb) * 64 + L) * 8);

    const int u_lane = wave * 16 + l15;
    f32x4 biasv[4];
    #pragma unroll
    for (int g = 0; g < 4; g++) {
        float b = b_sum[g * D_H + u_lane];
        biasv[g] = (f32x4){b, b, b, b};
    }
    const float bo = (l15 < D_OUT) ? b_out[l15] : 0.0f;

    // per-thread A h-row write geometry (+ swizzle XOR, constant per thread)
    const int kb_u = 2 + (u_lane >> 5);
    const int fl   = ((u_lane >> 3) & 3) * 16 + quad * 4;
    const int j_u  = u_lane & 7;
    const int swzw = (((fl >> 3)) & 7) << 3;

    // ---- one-time LDS staging ----
    for (int i = tid; i < 3 * D_EMB; i += BLOCK) {
        if (i < 2 * D_EMB) We_s[i] = W_embed[i];
        else               be_s[i - 2 * D_EMB] = b_embed[i - 2 * D_EMB];
    }
    for (int i = tid; i < WOUT_ELEMS; i += BLOCK) WoS[i] = WoutF[i];

    // ---- h, c -> registers (c as cL = 2c*log2e); h -> A[0] h-rows ----
    float    cL[RT_N][4];
    unsigned hr[RT_N][4];                         // bf16 in low 16 bits
    #pragma unroll
    for (int rt = 0; rt < RT_N; rt++)
        #pragma unroll
        for (int r = 0; r < 4; r++) {
            int m = rt * 16 + quad * 4 + r;
            cL[rt][r] = AP2 * c0[(size_t)(n_base + m) * D_H + u_lane];
            hr[rt][r] = f2bf_hw(h0[(size_t)(n_base + m) * D_H + u_lane]);
            A[0][((((rt * 6 + kb_u) * 64 + fl + r) * 8) + j_u) ^ swzw] =
                (unsigned short)hr[rt][r];
        }

    // ---- emb mapping: 4 threads/node, 16 emb dims each (2 x b128) ----
    const int node_e = tid >> 2;
    const int eb2    = tid & 3;
    int idx_e[2];
    #pragma unroll
    for (int s = 0; s < 2; s++) {
        int e0 = eb2 * 16 + s * 8;
        int base = (((node_e >> 4) * 6 + (e0 >> 5)) * 64 +
                    ((e0 >> 3) & 3) * 16 + (node_e & 15)) * 8;
        int t_e  = ((((e0 >> 3) & 3) * 2 + ((node_e & 15) >> 3)) & 7) << 3;
        idx_e[s] = base ^ t_e;
    }

#define EMB_WRITE(AW, XV) do {                                                 \
    _Pragma("unroll")                                                          \
    for (int s = 0; s < 2; s++) {                                              \
        s16x8 ev;                                                              \
        _Pragma("unroll")                                                      \
        for (int j = 0; j < 8; j++) {                                          \
            int e = eb2 * 16 + s * 8 + j;                                      \
            float v = fmaf((XV).x, We_s[e], fmaf((XV).y, We_s[D_EMB + e], be_s[e])); \
            ev[j] = (short)f2bf_hw(fmaxf(v, 0.0f));                            \
        }                                                                      \
        *(s16x8*)((AW) + idx_e[s]) = ev;                                       \
    } } while (0)

    // ---- emb(0) + mask(0) -> A[0] ----
    {
        float2 x0 = *(const float2*)(nodes + (size_t)(n_base + node_e) * 2);
        EMB_WRITE(A[0], x0);
        int lm0 = (tid < MT) ? mask[n_base + tid] : 0;
        if (wave < 2) {
            unsigned long long bm = __ballot(lm0 != 0);
            if (L == 0) msk64[0][wave] = bm;
        }
    }
    __syncthreads();   // prologue barrier

// GEMM of one row-tile into acc slot rt&1; kb=0 MFMA uses biasv as C
#define GEMM_RT(rt) do {                                                       \
    {   s16x8 af0 = *(const s16x8*)(Ar + ((rt) * 6 + 0) * 512 + Lsw);          \
        _Pragma("unroll")                                                      \
        for (int g = 0; g < 4; g++)                                            \
            acc[(rt) & 1][g] = __builtin_amdgcn_mfma_f32_16x16x32_bf16(        \
                af0, Bf[g][0], biasv[g], 0, 0, 0); }                           \
    _Pragma("unroll")                                                          \
    for (int kb = 1; kb < 6; kb++) {                                           \
        s16x8 af = *(const s16x8*)(Ar + ((rt) * 6 + kb) * 512 + Lsw);          \
        _Pragma("unroll")                                                      \
        for (int g = 0; g < 4; g++)                                            \
            acc[(rt) & 1][g] = __builtin_amdgcn_mfma_f32_16x16x32_bf16(        \
                af, Bf[g][kb], acc[(rt) & 1][g], 0, 0, 0); }                   \
} while (0)

// Activations + state update + unconditional h-write (slot rt&1 freed after)
#define ACT_RT(rt, MW) do {                                                    \
    unsigned nib = (unsigned)((MW) >> (((rt) & 3) * 16 + quad * 4)) & 0xFu;    \
    _Pragma("unroll")                                                          \
    for (int r = 0; r < 4; r++) {                                              \
        float gi = sig_pre(acc[(rt) & 1][0][r]);                               \
        float gf = sig_pre(acc[(rt) & 1][1][r]);                               \
        float rg = sig_pre(acc[(rt) & 1][2][r]);                               \
        float go = sig_pre(acc[(rt) & 1][3][r]);                               \
        float ggL = fmaf(AM4, rg, AP2);            /* 2*log2e*tanh(g) */       \
        float cnL = fmaf(gf, cL[rt][r], gi * ggL); /* 2*log2e*c_new   */       \
        float rr  = __builtin_amdgcn_rcpf(1.0f + exp2f_fast(cnL));             \
        float hv  = go * fmaf(-2.0f, rr, 1.0f);    /* o*tanh(c_new)   */       \
        unsigned hb = f2bf_hw(hv);                                             \
        if ((nib >> r) & 1u) { cL[rt][r] = cnL; hr[rt][r] = hb; }              \
        Aw[(((((rt) * 6 + kb_u) * 64 + fl + r) * 8) + j_u) ^ swzw] =           \
            (unsigned short)hr[rt][r];                                         \
    } } while (0)

// out-proj for time TIDX from buffer ARP (h rows), mask words MPA/MPB (regs),
// direct masked global store: wave covers contiguous 320B.
#define OPROJ(ARP, TIDX, MPA, MPB) do {                                        \
    f32x4 ao = (f32x4){0.f, 0.f, 0.f, 0.f};                                    \
    _Pragma("unroll")                                                          \
    for (int kb2 = 0; kb2 < 4; kb2++) {                                        \
        s16x8 af = *(const s16x8*)((ARP) + (wave * 6 + 2 + kb2) * 512 + Lsw);  \
        s16x8 wf = *(const s16x8*)(WoS + (kb2 * 64 + L) * 8);                  \
        ao = __builtin_amdgcn_mfma_f32_16x16x32_bf16(af, wf, ao, 0, 0, 0);     \
    }                                                                          \
    if (l15 < D_OUT) {                                                         \
        unsigned long long Mw = (wave < 4) ? (MPA) : (MPB);                    \
        unsigned nib = (unsigned)(Mw >> ((wave & 3) * 16 + quad * 4)) & 0xFu;  \
        float* ob = out + ((size_t)(TIDX) * NN + n_base) * D_OUT + l15;        \
        _Pragma("unroll")                                                      \
        for (int r = 0; r < 4; r++) {                                          \
            int node = wave * 16 + quad * 4 + r;                               \
            ob[node * D_OUT] = ((nib >> r) & 1u) ? (ao[r] + bo) : 0.0f;        \
        }                                                                      \
    } } while (0)

    unsigned long long Mp0 = 0, Mp1 = 0;

    for (int t = 0; t < T_STEPS; t++) {
        unsigned short* __restrict__ Ar = A[t & 1];
        unsigned short* __restrict__ Aw = A[(t + 1) & 1];

        const unsigned long long M0 = msk64[t & 1][0];
        const unsigned long long M1 = msk64[t & 1][1];

        // prefetch x(t+1)/mask(t+1): consumed late
        float2 xv = make_float2(0.0f, 0.0f);
        int    lm = 0;
        if (t + 1 < T_STEPS) {
            xv = *(const float2*)(nodes + ((size_t)(t + 1) * NN + n_base + node_e) * 2);
            if (tid < MT) lm = mask[(size_t)(t + 1) * NN + n_base + tid];
        }

        f32x4 acc[2][4];
        GEMM_RT(0);
        GEMM_RT(1);
        ACT_RT(0, M0);
        GEMM_RT(2);
        ACT_RT(1, M0);
        GEMM_RT(3);
        ACT_RT(2, M0);
        if (t > 0) OPROJ(Ar, t - 1, Mp0, Mp1);
        ACT_RT(3, M0);
        GEMM_RT(4);
        GEMM_RT(5);
        ACT_RT(4, M1);
        GEMM_RT(6);
        ACT_RT(5, M1);
        GEMM_RT(7);
        ACT_RT(6, M1);
        if (t + 1 < T_STEPS) {
            EMB_WRITE(Aw, xv);
            if (wave < 2) {
                unsigned long long bm = __ballot(lm != 0);
                if (L == 0) msk64[(t + 1) & 1][wave] = bm;
            }
        }
        ACT_RT(7, M1);

        Mp0 = M0; Mp1 = M1;
        __syncthreads();   // THE barrier: nothing runs after it this step
    }

    // ---- epilogue: A[0] holds h(19); Mp = M(19) ----
    OPROJ(A[0], T_STEPS - 1, Mp0, Mp1);

    // h_fin: coalesced from A[0] (swizzle-aware)
    for (int i = tid; i < MT * D_H; i += BLOCK) {
        int node = i >> 7, u = i & 127;
        int base = (((node >> 4) * 6 + 2 + (u >> 5)) * 64 +
                    ((u >> 3) & 3) * 16 + (node & 15)) * 8 + (u & 7);
        int t_f  = ((((u >> 3) & 3) * 2 + ((node & 15) >> 3)) & 7) << 3;
        out[OFF_H + (size_t)(n_base + node) * D_H + u] = bf2f(A[0][base ^ t_f]);
    }

    // c_fin: LDS staging (stride 129), coalesced copy
    __syncthreads();                    // all A reads done
    float* cs = (float*)A;              // 128*129*4 = 66 KB of the 96 KB
    #pragma unroll
    for (int rt = 0; rt < RT_N; rt++)
        #pragma unroll
        for (int r = 0; r < 4; r++) {
            int m = rt * 16 + quad * 4 + r;
            cs[m * 129 + u_lane] = CINV * cL[rt][r];
        }
    __syncthreads();
    for (int i = tid; i < MT * D_H; i += BLOCK) {
        int node = i >> 7, u = i & 127;
        out[OFF_C + (size_t)(n_base + node) * D_H + u] = cs[node * 129 + u];
    }

#undef EMB_WRITE
#undef GEMM_RT
#undef ACT_RT
#undef OPROJ
}

extern "C" void kernel_launch(void* const* d_in, const int* in_sizes, int n_in,
                              void* d_out, int out_size, void* d_ws, size_t ws_size,
                              hipStream_t stream) {
    const float* nodes   = (const float*)d_in[0];
    const int*   mask    = (const int*)  d_in[1];
    const float* h0      = (const float*)d_in[2];
    const float* c0      = (const float*)d_in[3];
    const float* W_embed = (const float*)d_in[4];
    const float* b_embed = (const float*)d_in[5];
    const float* W_ih    = (const float*)d_in[6];
    const float* b_ih    = (const float*)d_in[7];
    const float* W_hh    = (const float*)d_in[8];
    const float* b_hh    = (const float*)d_in[9];
    const float* W_out   = (const float*)d_in[10];
    const float* b_out   = (const float*)d_in[11];
    float* out = (float*)d_out;

    unsigned short* Wp    = (unsigned short*)d_ws;
    unsigned short* WoutF = Wp + WP_ELEMS;
    float*          b_sum = (float*)(WoutF + WOUT_ELEMS);

    prepack_kernel<<<(WP_ELEMS + WOUT_ELEMS + 255) / 256, 256, 0, stream>>>(
        W_ih, b_ih, W_hh, b_hh, W_out, Wp, WoutF, b_sum);

    vlstm_kernel<<<GRID, BLOCK, 0, stream>>>(
        nodes, mask, h0, c0, W_embed, b_embed, b_out, Wp, WoutF, b_sum, out);
}

// Round 7
// 306.948 us; speedup vs baseline: 2.4471x; 1.0533x over previous
//
#include <hip/hip_runtime.h>
#include <cstddef>

// ============================================================================
// VLSTM via bf16 MFMA, R11: R8 verbatim + A-buffer XOR swizzle ONLY.
//  - R10 post-mortem: swizzle worked (bank conflicts 5.24M->786K) but biasv
//    (+12 VGPR) + 32-bit hr (+16 VGPR) spilled ~1.4 dwords/thread/step
//    (+14MB WRITE / +8MB FETCH scratch traffic, 201->248us). At 2 waves/SIMD
//    and 128-VGPR budget there is NO allocator slack: changes must be
//    register-neutral.
//  - This round: R8's exact register set (scalar bias in ACT, MFMA C=0,
//    ushort hr, __expf fallback) + swizzle (slot -> slot ^ (slot>>3) on all
//    A-buffer accesses; +2 VGPR). h-writes drop 8-way -> 2-way conflicts.
// ============================================================================

typedef __attribute__((ext_vector_type(8))) short  s16x8;   // 8 x bf16
typedef __attribute__((ext_vector_type(4))) float  f32x4;

namespace {
constexpr int T_STEPS = 20;
constexpr int NN      = 32768;
constexpr int D_EMB   = 64;
constexpr int D_H     = 128;
constexpr int D_OUT   = 5;
constexpr int G4      = 512;
constexpr int MT      = 128;                  // nodes per block
constexpr int BLOCK   = 512;
constexpr int GRID    = NN / MT;              // 256 blocks = 256 CUs
constexpr int RT_N    = MT / 16;              // 8 row-tiles
constexpr int WP_ELEMS   = 8 * 4 * 6 * 64 * 8;
constexpr int WOUT_ELEMS = 4 * 64 * 8;
constexpr int A_ELEMS    = RT_N * 6 * 64 * 8;   // 24576 shorts = 48 KB / buf
constexpr float LOG2E = 1.4426950408889634f;
constexpr float AM4   = -4.0f * LOG2E;
constexpr float AP2   =  2.0f * LOG2E;
constexpr float CINV  = 0.34657359027997264f;   // 1/(2*log2e)
constexpr size_t OFF_H = (size_t)T_STEPS * NN * D_OUT;
constexpr size_t OFF_C = OFF_H + (size_t)NN * D_H;
}

__device__ __forceinline__ unsigned short f2bf(float x) {
    unsigned u = __float_as_uint(x);
    u = (u + 0x7FFFu + ((u >> 16) & 1u)) >> 16;     // RNE
    return (unsigned short)u;
}
__device__ __forceinline__ unsigned short f2bf_hw(float x) {
    __bf16 b = (__bf16)x;
    union { __bf16 b; unsigned short u; } cv;
    cv.b = b;
    return cv.u;
}
__device__ __forceinline__ float bf2f(unsigned short h) {
    return __uint_as_float(((unsigned)h) << 16);
}
__device__ __forceinline__ float exp2f_fast(float x) {
#if __has_builtin(__builtin_amdgcn_exp2f)
    return __builtin_amdgcn_exp2f(x);
#else
    return __expf(x * 0.6931471805599453f);
#endif
}
__device__ __forceinline__ float sig_pre(float a) {   // sigmoid, a = -x*log2e
    return __builtin_amdgcn_rcpf(1.0f + exp2f_fast(a));
}

// ----------------------------------------------------------------------------
__global__ void prepack_kernel(const float* __restrict__ W_ih,
                               const float* __restrict__ b_ih,
                               const float* __restrict__ W_hh,
                               const float* __restrict__ b_hh,
                               const float* __restrict__ W_out,
                               unsigned short* __restrict__ Wp,
                               unsigned short* __restrict__ WoutF,
                               float* __restrict__ b_sum) {
    int idx = blockIdx.x * blockDim.x + threadIdx.x;
    if (idx < WP_ELEMS) {
        int j    = idx & 7;
        int L    = (idx >> 3) & 63;
        int rest = idx >> 9;
        int kb   = rest % 6;
        int gw   = rest / 6;
        int g    = gw & 3, w = gw >> 2;
        int k    = kb * 32 + (L >> 4) * 8 + j;
        int col  = g * D_H + w * 16 + (L & 15);
        float v  = (k < D_EMB) ? W_ih[k * G4 + col] : W_hh[(k - D_EMB) * G4 + col];
        float s  = (g == 2) ? (2.0f * LOG2E) : (-LOG2E);
        Wp[idx] = f2bf(v * s);
    } else if (idx < WP_ELEMS + WOUT_ELEMS) {
        int i2 = idx - WP_ELEMS;
        int j = i2 & 7, L = (i2 >> 3) & 63, kb2 = i2 >> 9;
        int k = kb2 * 32 + (L >> 4) * 8 + j;
        int n = L & 15;
        WoutF[i2] = (n < D_OUT) ? f2bf(W_out[k * D_OUT + n]) : (unsigned short)0;
    }
    if (idx < G4) {
        int g = idx / D_H;
        float s = (g == 2) ? (2.0f * LOG2E) : (-LOG2E);
        b_sum[idx] = (b_ih[idx] + b_hh[idx]) * s;
    }
}

// ----------------------------------------------------------------------------
__global__ __launch_bounds__(BLOCK, 2) void vlstm_kernel(
    const float* __restrict__ nodes,   // [T][N][2]
    const int*   __restrict__ mask,    // [T][N]
    const float* __restrict__ h0,      // [N][128]
    const float* __restrict__ c0,      // [N][128]
    const float* __restrict__ W_embed, // [2][64]
    const float* __restrict__ b_embed, // [64]
    const float* __restrict__ b_out,   // [5]
    const unsigned short* __restrict__ Wp,
    const unsigned short* __restrict__ WoutF,
    const float* __restrict__ b_sum,
    float* __restrict__ out)
{
    __shared__ __align__(16) unsigned short A[2][A_ELEMS];   // 96 KB dbuf
    __shared__ __align__(16) unsigned short WoS[WOUT_ELEMS]; // 4 KB
    __shared__ float We_s[2 * D_EMB];
    __shared__ float be_s[D_EMB];
    __shared__ __align__(16) unsigned long long msk64[2][2];

    const int tid  = threadIdx.x;
    const int wave = tid >> 6;
    const int L    = tid & 63;
    const int quad = L >> 4;
    const int l15  = L & 15;
    const int n_base = blockIdx.x * MT;

    // swizzled lane base for all A-frag reads (GEMM + OPROJ), in shorts
    const int Lsw = (L * 8) ^ (((L >> 3) & 7) << 3);

    // ---- gate weights -> registers, once (96 VGPR/wave) ----
    const unsigned short* wbase = Wp + (size_t)wave * (4 * 6 * 64 * 8);
    s16x8 Bf[4][6];
    #pragma unroll
    for (int g = 0; g < 4; g++)
        #pragma unroll
        for (int kb = 0; kb < 6; kb++)
            Bf[g][kb] = *(const s16x8*)(wbase + ((g * 6 + kb) * 64 + L) * 8);

    const int u_lane = wave * 16 + l15;
    float bias[4];
    #pragma unroll
    for (int g = 0; g < 4; g++) bias[g] = b_sum[g * D_H + u_lane];
    const float bo = (l15 < D_OUT) ? b_out[l15] : 0.0f;

    // per-thread A h-row write geometry (+ swizzle XOR, constant per thread)
    const int kb_u = 2 + (u_lane >> 5);
    const int fl   = ((u_lane >> 3) & 3) * 16 + quad * 4;
    const int j_u  = u_lane & 7;
    const int swzw = ((fl >> 3) & 7) << 3;

    // ---- one-time LDS staging ----
    for (int i = tid; i < 3 * D_EMB; i += BLOCK) {
        if (i < 2 * D_EMB) We_s[i] = W_embed[i];
        else               be_s[i - 2 * D_EMB] = b_embed[i - 2 * D_EMB];
    }
    for (int i = tid; i < WOUT_ELEMS; i += BLOCK) WoS[i] = WoutF[i];

    // ---- h, c -> registers (c as cL = 2c*log2e); h -> A[0] h-rows ----
    float          cL[RT_N][4];
    unsigned short hr[RT_N][4];
    #pragma unroll
    for (int rt = 0; rt < RT_N; rt++)
        #pragma unroll
        for (int r = 0; r < 4; r++) {
            int m = rt * 16 + quad * 4 + r;
            cL[rt][r] = AP2 * c0[(size_t)(n_base + m) * D_H + u_lane];
            hr[rt][r] = f2bf_hw(h0[(size_t)(n_base + m) * D_H + u_lane]);
            A[0][((((rt * 6 + kb_u) * 64 + fl + r) * 8) + j_u) ^ swzw] = hr[rt][r];
        }

    // ---- emb mapping: 4 threads/node, 16 emb dims each (2 x b128) ----
    const int node_e = tid >> 2;
    const int eb2    = tid & 3;
    int idx_e[2];
    #pragma unroll
    for (int s = 0; s < 2; s++) {
        int e0 = eb2 * 16 + s * 8;
        int base = (((node_e >> 4) * 6 + (e0 >> 5)) * 64 +
                    ((e0 >> 3) & 3) * 16 + (node_e & 15)) * 8;
        int t_e  = ((((e0 >> 3) & 3) * 2 + ((node_e & 15) >> 3)) & 7) << 3;
        idx_e[s] = base ^ t_e;
    }

#define EMB_WRITE(AW, XV) do {                                                 \
    _Pragma("unroll")                                                          \
    for (int s = 0; s < 2; s++) {                                              \
        s16x8 ev;                                                              \
        _Pragma("unroll")                                                      \
        for (int j = 0; j < 8; j++) {                                          \
            int e = eb2 * 16 + s * 8 + j;                                      \
            float v = fmaf((XV).x, We_s[e], fmaf((XV).y, We_s[D_EMB + e], be_s[e])); \
            ev[j] = (short)f2bf_hw(fmaxf(v, 0.0f));                            \
        }                                                                      \
        *(s16x8*)((AW) + idx_e[s]) = ev;                                       \
    } } while (0)

    // ---- emb(0) + mask(0) -> A[0] ----
    {
        float2 x0 = *(const float2*)(nodes + (size_t)(n_base + node_e) * 2);
        EMB_WRITE(A[0], x0);
        int lm0 = (tid < MT) ? mask[n_base + tid] : 0;
        if (wave < 2) {
            unsigned long long bm = __ballot(lm0 != 0);
            if (L == 0) msk64[0][wave] = bm;
        }
    }
    __syncthreads();   // prologue barrier

// GEMM of one row-tile into acc slot rt&1; MFMA C=0 inline on kb=0
#define GEMM_RT(rt) do {                                                       \
    {   s16x8 af0 = *(const s16x8*)(Ar + ((rt) * 6 + 0) * 512 + Lsw);          \
        _Pragma("unroll")                                                      \
        for (int g = 0; g < 4; g++)                                            \
            acc[(rt) & 1][g] = __builtin_amdgcn_mfma_f32_16x16x32_bf16(        \
                af0, Bf[g][0], (f32x4){0.f, 0.f, 0.f, 0.f}, 0, 0, 0); }        \
    _Pragma("unroll")                                                          \
    for (int kb = 1; kb < 6; kb++) {                                           \
        s16x8 af = *(const s16x8*)(Ar + ((rt) * 6 + kb) * 512 + Lsw);          \
        _Pragma("unroll")                                                      \
        for (int g = 0; g < 4; g++)                                            \
            acc[(rt) & 1][g] = __builtin_amdgcn_mfma_f32_16x16x32_bf16(        \
                af, Bf[g][kb], acc[(rt) & 1][g], 0, 0, 0); }                   \
} while (0)

// Activations + state update + unconditional h-write (slot rt&1 freed after)
#define ACT_RT(rt, MW) do {                                                    \
    unsigned nib = (unsigned)((MW) >> (((rt) & 3) * 16 + quad * 4)) & 0xFu;    \
    _Pragma("unroll")                                                          \
    for (int r = 0; r < 4; r++) {                                              \
        float gi = sig_pre(acc[(rt) & 1][0][r] + bias[0]);                     \
        float gf = sig_pre(acc[(rt) & 1][1][r] + bias[1]);                     \
        float rg = sig_pre(acc[(rt) & 1][2][r] + bias[2]);                     \
        float go = sig_pre(acc[(rt) & 1][3][r] + bias[3]);                     \
        float ggL = fmaf(AM4, rg, AP2);            /* 2*log2e*tanh(g) */       \
        float cnL = fmaf(gf, cL[rt][r], gi * ggL); /* 2*log2e*c_new   */       \
        float rr  = __builtin_amdgcn_rcpf(1.0f + exp2f_fast(cnL));             \
        float hv  = go * fmaf(-2.0f, rr, 1.0f);    /* o*tanh(c_new)   */       \
        unsigned short hb = f2bf_hw(hv);                                       \
        if ((nib >> r) & 1u) { cL[rt][r] = cnL; hr[rt][r] = hb; }              \
        Aw[(((((rt) * 6 + kb_u) * 64 + fl + r) * 8) + j_u) ^ swzw] = hr[rt][r];\
    } } while (0)

// out-proj for time TIDX from buffer ARP (h rows), mask words MPA/MPB (regs),
// direct masked global store: wave covers contiguous 320B.
#define OPROJ(ARP, TIDX, MPA, MPB) do {                                        \
    f32x4 ao = (f32x4){0.f, 0.f, 0.f, 0.f};                                    \
    _Pragma("unroll")                                                          \
    for (int kb2 = 0; kb2 < 4; kb2++) {                                        \
        s16x8 af = *(const s16x8*)((ARP) + (wave * 6 + 2 + kb2) * 512 + Lsw);  \
        s16x8 wf = *(const s16x8*)(WoS + (kb2 * 64 + L) * 8);                  \
        ao = __builtin_amdgcn_mfma_f32_16x16x32_bf16(af, wf, ao, 0, 0, 0);     \
    }                                                                          \
    if (l15 < D_OUT) {                                                         \
        unsigned long long Mw = (wave < 4) ? (MPA) : (MPB);                    \
        unsigned nib = (unsigned)(Mw >> ((wave & 3) * 16 + quad * 4)) & 0xFu;  \
        float* ob = out + ((size_t)(TIDX) * NN + n_base) * D_OUT + l15;        \
        _Pragma("unroll")                                                      \
        for (int r = 0; r < 4; r++) {                                          \
            int node = wave * 16 + quad * 4 + r;                               \
            ob[node * D_OUT] = ((nib >> r) & 1u) ? (ao[r] + bo) : 0.0f;        \
        }                                                                      \
    } } while (0)

    unsigned long long Mp0 = 0, Mp1 = 0;

    for (int t = 0; t < T_STEPS; t++) {
        unsigned short* __restrict__ Ar = A[t & 1];
        unsigned short* __restrict__ Aw = A[(t + 1) & 1];

        const unsigned long long M0 = msk64[t & 1][0];
        const unsigned long long M1 = msk64[t & 1][1];

        // prefetch x(t+1)/mask(t+1): consumed late
        float2 xv = make_float2(0.0f, 0.0f);
        int    lm = 0;
        if (t + 1 < T_STEPS) {
            xv = *(const float2*)(nodes + ((size_t)(t + 1) * NN + n_base + node_e) * 2);
            if (tid < MT) lm = mask[(size_t)(t + 1) * NN + n_base + tid];
        }

        f32x4 acc[2][4];
        GEMM_RT(0);
        GEMM_RT(1);
        ACT_RT(0, M0);
        GEMM_RT(2);
        ACT_RT(1, M0);
        GEMM_RT(3);
        ACT_RT(2, M0);
        if (t > 0) OPROJ(Ar, t - 1, Mp0, Mp1);
        ACT_RT(3, M0);
        GEMM_RT(4);
        GEMM_RT(5);
        ACT_RT(4, M1);
        GEMM_RT(6);
        ACT_RT(5, M1);
        GEMM_RT(7);
        ACT_RT(6, M1);
        if (t + 1 < T_STEPS) {
            EMB_WRITE(Aw, xv);
            if (wave < 2) {
                unsigned long long bm = __ballot(lm != 0);
                if (L == 0) msk64[(t + 1) & 1][wave] = bm;
            }
        }
        ACT_RT(7, M1);

        Mp0 = M0; Mp1 = M1;
        __syncthreads();   // THE barrier: nothing runs after it this step
    }

    // ---- epilogue: A[0] holds h(19); Mp = M(19) ----
    OPROJ(A[0], T_STEPS - 1, Mp0, Mp1);

    // h_fin: coalesced from A[0] (swizzle-aware)
    for (int i = tid; i < MT * D_H; i += BLOCK) {
        int node = i >> 7, u = i & 127;
        int base = (((node >> 4) * 6 + 2 + (u >> 5)) * 64 +
                    ((u >> 3) & 3) * 16 + (node & 15)) * 8 + (u & 7);
        int t_f  = ((((u >> 3) & 3) * 2 + ((node & 15) >> 3)) & 7) << 3;
        out[OFF_H + (size_t)(n_base + node) * D_H + u] = bf2f(A[0][base ^ t_f]);
    }

    // c_fin: LDS staging (stride 129), coalesced copy
    __syncthreads();                    // all A reads done
    float* cs = (float*)A;              // 128*129*4 = 66 KB of the 96 KB
    #pragma unroll
    for (int rt = 0; rt < RT_N; rt++)
        #pragma unroll
        for (int r = 0; r < 4; r++) {
            int m = rt * 16 + quad * 4 + r;
            cs[m * 129 + u_lane] = CINV * cL[rt][r];
        }
    __syncthreads();
    for (int i = tid; i < MT * D_H; i += BLOCK) {
        int node = i >> 7, u = i & 127;
        out[OFF_C + (size_t)(n_base + node) * D_H + u] = cs[node * 129 + u];
    }

#undef EMB_WRITE
#undef GEMM_RT
#undef ACT_RT
#undef OPROJ
}

extern "C" void kernel_launch(void* const* d_in, const int* in_sizes, int n_in,
                              void* d_out, int out_size, void* d_ws, size_t ws_size,
                              hipStream_t stream) {
    const float* nodes   = (const float*)d_in[0];
    const int*   mask    = (const int*)  d_in[1];
    const float* h0      = (const float*)d_in[2];
    const float* c0      = (const float*)d_in[3];
    const float* W_embed = (const float*)d_in[4];
    const float* b_embed = (const float*)d_in[5];
    const float* W_ih    = (const float*)d_in[6];
    const float* b_ih    = (const float*)d_in[7];
    const float* W_hh    = (const float*)d_in[8];
    const float* b_hh    = (const float*)d_in[9];
    const float* W_out   = (const float*)d_in[10];
    const float* b_out   = (const float*)d_in[11];
    float* out = (float*)d_out;

    unsigned short* Wp    = (unsigned short*)d_ws;
    unsigned short* WoutF = Wp + WP_ELEMS;
    float*          b_sum = (float*)(WoutF + WOUT_ELEMS);

    prepack_kernel<<<(WP_ELEMS + WOUT_ELEMS + 255) / 256, 256, 0, stream>>>(
        W_ih, b_ih, W_hh, b_hh, W_out, Wp, WoutF, b_sum);

    vlstm_kernel<<<GRID, BLOCK, 0, stream>>>(
        nodes, mask, h0, c0, W_embed, b_embed, b_out, Wp, WoutF, b_sum, out);
}